// Round 1
// baseline (1100.023 us; speedup 1.0000x reference)
//
#include <hip/hip_runtime.h>

#define B_ 8
#define C_ 256
#define HIN 160
#define NH 23
#define NWIN 529
#define G5 5
#define NGRP 106
#define OPLANE 25600

typedef short bf16x8 __attribute__((ext_vector_type(8)));
typedef float f32x4 __attribute__((ext_vector_type(4)));
typedef unsigned short u16x4 __attribute__((ext_vector_type(4)));

__device__ __forceinline__ unsigned short f2bf(float f) {
    union { float f; unsigned u; } v; v.f = f;
    unsigned r = v.u + 0x7FFFu + ((v.u >> 16) & 1u);
    return (unsigned short)(r >> 16);
}

// ---------------- prep: Wv -> bf16, Wq/Wk -> transposed [c][ch] fp32 ----------------
__global__ void kprep(const float* __restrict__ Wq, const float* __restrict__ Wk,
                      const float* __restrict__ Wv, unsigned short* __restrict__ WvB,
                      float* __restrict__ Wqt, float* __restrict__ Wkt) {
    int t = blockIdx.x * 256 + threadIdx.x;
    if (t < 65536) WvB[t] = f2bf(Wv[t]);
    if (t < 8192) {
        int ch = t >> 8, c = t & 255;
        Wqt[c * 32 + ch] = Wq[t];
        Wkt[c * 32 + ch] = Wk[t];
    }
}

// ---------------- k12: per-pixel Q/K (fp32, SGPR weights) + S partial accumulation ----------------
__launch_bounds__(256, 2)
__global__ void k12(const float* __restrict__ x, const float* __restrict__ Wqt,
                    const float* __restrict__ Wkt, const float* __restrict__ bq,
                    const float* __restrict__ bk, float* __restrict__ Spart) {
    __shared__ float QLs[G5 * 32 * 50 + 8];
    __shared__ float KLs[G5 * 32 * 50 + 8];
    int t = threadIdx.x;
    int b = blockIdx.x / NGRP;
    int grp = blockIdx.x % NGRP;
    int win0 = grp * G5;

    if (t < 245) {
        int wloc = t / 49, p = t % 49;
        int win = win0 + wloc;
        float accQ[32], accK[32];
        if (win < NWIN) {
#pragma unroll
            for (int ch = 0; ch < 32; ++ch) { accQ[ch] = bq[ch]; accK[ch] = bk[ch]; }
            int wy = win / NH, wx = win % NH;
            int gy = wy * 7 + p / 7, gx = wx * 7 + p % 7;
            int sy = (gy < HIN) ? gy : 158;   // reflect pad: 160 -> 158
            int sx = (gx < HIN) ? gx : 158;
            const float* xp = x + (long)b * C_ * OPLANE + sy * HIN + sx;
            for (int c = 0; c < 256; ++c) {
                float xv = xp[c * OPLANE];
#pragma unroll
                for (int ch = 0; ch < 32; ++ch) {
                    accQ[ch] = fmaf(Wqt[c * 32 + ch], xv, accQ[ch]);
                    accK[ch] = fmaf(Wkt[c * 32 + ch], xv, accK[ch]);
                }
            }
        } else {
#pragma unroll
            for (int ch = 0; ch < 32; ++ch) { accQ[ch] = 0.f; accK[ch] = 0.f; }
        }
#pragma unroll
        for (int ch = 0; ch < 32; ++ch) {
            QLs[(wloc * 32 + ch) * 50 + p] = accQ[ch];
            KLs[(wloc * 32 + ch) * 50 + p] = accK[ch];
        }
    }
    __syncthreads();

    if (t < 169) {
        int p0 = (t / 13) * 4, q0 = (t % 13) * 4;
        float acc[4][4];
#pragma unroll
        for (int r = 0; r < 4; ++r)
#pragma unroll
            for (int cc = 0; cc < 4; ++cc) acc[r][cc] = 0.f;
        for (int w = 0; w < G5; ++w) {
            for (int ch = 0; ch < 32; ++ch) {
                const float* qr = &QLs[(w * 32 + ch) * 50 + p0];
                const float* kr = &KLs[(w * 32 + ch) * 50 + q0];
                float qv[4] = {qr[0], qr[1], qr[2], qr[3]};
                float kv[4] = {kr[0], kr[1], kr[2], kr[3]};
#pragma unroll
                for (int r = 0; r < 4; ++r)
#pragma unroll
                    for (int cc = 0; cc < 4; ++cc)
                        acc[r][cc] = fmaf(qv[r], kv[cc], acc[r][cc]);
            }
        }
        float* sp = Spart + (long)(b * NGRP + grp) * 2401;
#pragma unroll
        for (int r = 0; r < 4; ++r) {
            int p = p0 + r;
            if (p < 49) {
#pragma unroll
                for (int cc = 0; cc < 4; ++cc) {
                    int q = q0 + cc;
                    if (q < 49) sp[p * 49 + q] = acc[r][cc];
                }
            }
        }
    }
}

// ---------------- k2b: reduce partials + row softmax -> zero-padded bf16 attn [8][64][64] ----------------
__global__ void k2b(const float* __restrict__ Spart, unsigned short* __restrict__ attnP) {
    int b = blockIdx.x, t = threadIdx.x;
    __shared__ float S[2401];
    for (int idx = t; idx < 2401; idx += 256) {
        float s = 0.f;
        for (int g = 0; g < NGRP; ++g) s += Spart[(long)(b * NGRP + g) * 2401 + idx];
        S[idx] = s;
    }
    __syncthreads();
    if (t < 64) {
        unsigned short* row = attnP + (b * 64 + t) * 64;
        if (t < 49) {
            float m = -1e30f;
            for (int j = 0; j < 49; ++j) m = fmaxf(m, S[t * 49 + j]);
            float den = 0.f;
            for (int j = 0; j < 49; ++j) den += expf(S[t * 49 + j] - m);
            float inv = 1.f / den;
            for (int j = 0; j < 49; ++j) row[j] = f2bf(expf(S[t * 49 + j] - m) * inv);
            for (int j = 49; j < 64; ++j) row[j] = 0;
        } else {
            for (int j = 0; j < 64; ++j) row[j] = 0;
        }
    }
}

// ---------------- k3: fused  Y = X·attn^T  (MFMA-1)  then  OUT = Wv·Y + bv  (MFMA-2) ----------------
__launch_bounds__(256, 2)
__global__ void k3(const float* __restrict__ x, const unsigned short* __restrict__ WvB,
                   const unsigned short* __restrict__ attnP, const float* __restrict__ bv,
                   float* __restrict__ out) {
    __shared__ __align__(16) unsigned short Xc[256 * 40];   // [c][j-half(32)+pad8] bf16
    __shared__ __align__(16) unsigned short Yt[64 * 264];   // [i][c(256)+pad8] bf16

    int t = threadIdx.x;
    int bw = blockIdx.x;
    int b = bw / NWIN, win = bw % NWIN;
    int wy = win / NH, wx = win % NH;
    int lane = t & 63;
    int r16 = lane & 15, quad = lane >> 4, q8 = quad * 8;
    int w64 = (t >> 6) * 64;

    f32x4 zero = {0.f, 0.f, 0.f, 0.f};
    f32x4 acc1[4][4];
#pragma unroll
    for (int i = 0; i < 4; ++i)
#pragma unroll
        for (int j = 0; j < 4; ++j) acc1[i][j] = zero;

    const float* xb = x + (long)b * C_ * OPLANE;

    // ---- MFMA-1: D'[c][i] = sum_j X[c][j] * attn[i][j], K split into two 32-wide halves ----
    for (int half = 0; half < 2; ++half) {
        int jbase = half * 32;
        for (int idx = t; idx < 256 * 32; idx += 256) {
            int c = idx >> 5, j0 = idx & 31, j = jbase + j0;
            float v = 0.f;
            if (j < 49) {
                int gy = wy * 7 + j / 7, gx = wx * 7 + j % 7;
                int sy = (gy < HIN) ? gy : 158;
                int sx = (gx < HIN) ? gx : 158;
                v = xb[c * OPLANE + sy * HIN + sx];
            }
            Xc[c * 40 + j0] = f2bf(v);
        }
        __syncthreads();

        int k0 = jbase;
        bf16x8 a[4], bfr[4];
#pragma unroll
        for (int mt = 0; mt < 4; ++mt)
            a[mt] = *(const bf16x8*)&Xc[(w64 + mt * 16 + r16) * 40 + q8];
#pragma unroll
        for (int nt = 0; nt < 4; ++nt)
            bfr[nt] = *(const bf16x8*)&attnP[(b * 64 + nt * 16 + r16) * 64 + k0 + q8];
#pragma unroll
        for (int mt = 0; mt < 4; ++mt)
#pragma unroll
            for (int nt = 0; nt < 4; ++nt)
                acc1[mt][nt] = __builtin_amdgcn_mfma_f32_16x16x32_bf16(a[mt], bfr[nt], acc1[mt][nt], 0, 0, 0);
        __syncthreads();
    }

    // ---- store D' transposed into Yt[i][c] (4 consecutive c per lane -> b64 writes) ----
#pragma unroll
    for (int mt = 0; mt < 4; ++mt) {
        int cb = w64 + mt * 16 + quad * 4;
#pragma unroll
        for (int nt = 0; nt < 4; ++nt) {
            int ic = nt * 16 + r16;
            u16x4 pk;
            pk[0] = f2bf(acc1[mt][nt][0]);
            pk[1] = f2bf(acc1[mt][nt][1]);
            pk[2] = f2bf(acc1[mt][nt][2]);
            pk[3] = f2bf(acc1[mt][nt][3]);
            *(u16x4*)&Yt[ic * 264 + cb] = pk;
        }
    }
    __syncthreads();

    // ---- MFMA-2: OUT[ch][i] = sum_c Wv[ch][c] * Y[c][i] ----
    f32x4 acc2[4][4];
#pragma unroll
    for (int i = 0; i < 4; ++i)
#pragma unroll
        for (int j = 0; j < 4; ++j) acc2[i][j] = zero;

#pragma unroll
    for (int ks = 0; ks < 8; ++ks) {
        int k0 = ks * 32;
        bf16x8 a[4], bb[4];
#pragma unroll
        for (int mt = 0; mt < 4; ++mt)
            a[mt] = *(const bf16x8*)&WvB[(w64 + mt * 16 + r16) * 256 + k0 + q8];
#pragma unroll
        for (int nt = 0; nt < 4; ++nt)
            bb[nt] = *(const bf16x8*)&Yt[(nt * 16 + r16) * 264 + k0 + q8];
#pragma unroll
        for (int mt = 0; mt < 4; ++mt)
#pragma unroll
            for (int nt = 0; nt < 4; ++nt)
                acc2[mt][nt] = __builtin_amdgcn_mfma_f32_16x16x32_bf16(a[mt], bb[nt], acc2[mt][nt], 0, 0, 0);
    }

    // ---- epilogue: crop-write, f = win*49 + i -> (y,x) in 161x161, keep y<160 && x<160 ----
    float* ob = out + (long)b * C_ * OPLANE;
#pragma unroll
    for (int nt = 0; nt < 4; ++nt) {
        int i = nt * 16 + r16;
        if (i >= 49) continue;
        int f = win * 49 + i;
        int y = f / 161, xcol = f % 161;
        if (y >= 160 || xcol >= 160) continue;
        int dst = y * 160 + xcol;
#pragma unroll
        for (int mt = 0; mt < 4; ++mt) {
            int cb = w64 + mt * 16 + quad * 4;
#pragma unroll
            for (int r = 0; r < 4; ++r) {
                int ch = cb + r;
                ob[ch * OPLANE + dst] = acc2[mt][nt][r] + bv[ch];
            }
        }
    }
}

extern "C" void kernel_launch(void* const* d_in, const int* in_sizes, int n_in,
                              void* d_out, int out_size, void* d_ws, size_t ws_size,
                              hipStream_t stream) {
    const float* x  = (const float*)d_in[0];
    const float* Wq = (const float*)d_in[1];
    const float* bq = (const float*)d_in[2];
    const float* Wk = (const float*)d_in[3];
    const float* bk = (const float*)d_in[4];
    const float* Wv = (const float*)d_in[5];
    const float* bv = (const float*)d_in[6];
    float* out = (float*)d_out;

    char* ws = (char*)d_ws;
    unsigned short* WvB  = (unsigned short*)(ws);                       // 131072 B
    float* Wqt           = (float*)(ws + 131072);                       // 32768 B
    float* Wkt           = (float*)(ws + 163840);                       // 32768 B
    float* Spart         = (float*)(ws + 196608);                       // 8*106*2401*4 = 8144192 B
    unsigned short* attnP = (unsigned short*)(ws + 196608 + 8144192);   // 65536 B

    kprep<<<dim3(256), dim3(256), 0, stream>>>(Wq, Wk, Wv, WvB, Wqt, Wkt);
    k12<<<dim3(8 * NGRP), dim3(256), 0, stream>>>(x, Wqt, Wkt, bq, bk, Spart);
    k2b<<<dim3(8), dim3(256), 0, stream>>>(Spart, attnP);
    k3<<<dim3(8 * NWIN), dim3(256), 0, stream>>>(x, WvB, attnP, bv, out);
}

// Round 2
// 742.906 us; speedup vs baseline: 1.4807x; 1.4807x over previous
//
#include <hip/hip_runtime.h>

#define C_ 256
#define HIN 160
#define NH 23
#define NWIN 529
#define G5 5
#define NGRP 106
#define OPLANE 25600

typedef short bf16x8 __attribute__((ext_vector_type(8)));
typedef float f32x4 __attribute__((ext_vector_type(4)));
typedef unsigned short u16x4 __attribute__((ext_vector_type(4)));

__device__ __forceinline__ unsigned short f2bf(float f) {
    union { float f; unsigned u; } v; v.f = f;
    unsigned r = v.u + 0x7FFFu + ((v.u >> 16) & 1u);
    return (unsigned short)(r >> 16);
}

// ---------------- prep: Wv -> bf16; Wq,Wk -> stacked transposed W2t[c][64] ----------------
__global__ void kprep(const float* __restrict__ Wq, const float* __restrict__ Wk,
                      const float* __restrict__ Wv, unsigned short* __restrict__ WvB,
                      float* __restrict__ W2t) {
    int t = blockIdx.x * 256 + threadIdx.x;
    if (t < 65536) WvB[t] = f2bf(Wv[t]);
    if (t < 16384) {
        int c = t >> 6, ch = t & 63;
        W2t[c * 64 + ch] = (ch < 32) ? Wq[ch * 256 + c] : Wk[(ch - 32) * 256 + c];
    }
}

// ---------------- k12: tiled QK-GEMM (fp32) + S partial accumulation ----------------
#define QST 260   // QKs row stride (floats)
#define XST 264   // Xs row stride (floats)
__launch_bounds__(256, 2)
__global__ void k12(const float* __restrict__ x, const float* __restrict__ W2t,
                    const float* __restrict__ bq, const float* __restrict__ bk,
                    float* __restrict__ Spart) {
    __shared__ float QKs[64 * QST];        // 66560 B
    __shared__ float Xs[8 * XST];          // 8448 B
    __shared__ float Ws[8 * 64];           // 2048 B

    int t = threadIdx.x;
    int g = blockIdx.x;
    int b = g & 7;            // XCD swizzle: one batch per XCD
    int grp = g >> 3;
    int win0 = grp * G5;

    // pixel handled by this thread's staging column
    int wloc = t / 49, p = t % 49;
    int win = win0 + wloc;
    bool pxvalid = (t < 245) && (win < NWIN);
    const float* xp = x;
    if (pxvalid) {
        int wy = win / NH, wx = win % NH;
        int gy = wy * 7 + p / 7, gx = wx * 7 + p % 7;
        int sy = (gy < HIN) ? gy : 158;
        int sx = (gx < HIN) ? gx : 158;
        xp = x + (long)b * C_ * OPLANE + sy * HIN + sx;
    }

    int tx = t & 31, ty = t >> 5;

    float acc[8][8];
#pragma unroll
    for (int i = 0; i < 8; ++i)
#pragma unroll
        for (int j = 0; j < 8; ++j) acc[i][j] = 0.f;

    float prefX[8], prefW[2];
#pragma unroll
    for (int e = 0; e < 8; ++e) prefX[e] = pxvalid ? xp[(long)e * OPLANE] : 0.f;
#pragma unroll
    for (int i = 0; i < 2; ++i) {
        int idx = i * 256 + t, e = idx >> 6, ch = idx & 63;
        prefW[i] = W2t[e * 64 + ch];
    }

    for (int c0 = 0; c0 < 256; c0 += 8) {
#pragma unroll
        for (int e = 0; e < 8; ++e) Xs[e * XST + t] = prefX[e];
#pragma unroll
        for (int i = 0; i < 2; ++i) {
            int idx = i * 256 + t, e = idx >> 6, ch = idx & 63;
            Ws[e * 64 + ch] = prefW[i];
        }
        __syncthreads();
        if (c0 + 8 < 256) {
            int c1 = c0 + 8;
#pragma unroll
            for (int e = 0; e < 8; ++e) prefX[e] = pxvalid ? xp[(long)(c1 + e) * OPLANE] : 0.f;
#pragma unroll
            for (int i = 0; i < 2; ++i) {
                int idx = i * 256 + t, e = idx >> 6, ch = idx & 63;
                prefW[i] = W2t[(c1 + e) * 64 + ch];
            }
        }
#pragma unroll
        for (int kk = 0; kk < 8; ++kk) {
            float wv[8], xv[8];
#pragma unroll
            for (int i = 0; i < 8; ++i) wv[i] = Ws[kk * 64 + ty * 8 + i];
#pragma unroll
            for (int i = 0; i < 8; ++i) xv[i] = Xs[kk * XST + tx * 8 + i];
#pragma unroll
            for (int ci = 0; ci < 8; ++ci)
#pragma unroll
                for (int pi = 0; pi < 8; ++pi)
                    acc[ci][pi] = fmaf(wv[ci], xv[pi], acc[ci][pi]);
        }
        __syncthreads();
    }

    // epilogue: QKs[ch][px] = valid ? acc + bias : 0
    bool cvalid[8];
#pragma unroll
    for (int pi = 0; pi < 8; ++pi) {
        int px = tx * 8 + pi;
        int w = px / 49;
        cvalid[pi] = (px < 245) && (win0 + w < NWIN);
    }
    const float* bb = (ty < 4) ? (bq + ty * 8) : (bk + (ty - 4) * 8);
    float bias[8];
#pragma unroll
    for (int ci = 0; ci < 8; ++ci) bias[ci] = bb[ci];
#pragma unroll
    for (int ci = 0; ci < 8; ++ci) {
        int ch = ty * 8 + ci;
#pragma unroll
        for (int pi = 0; pi < 8; ++pi) {
            int px = tx * 8 + pi;
            QKs[ch * QST + px] = cvalid[pi] ? (acc[ci][pi] + bias[ci]) : 0.f;
        }
    }
    __syncthreads();

    // S partials: S[p][q] += sum_{w,ch} Q[ch,w,p] * K[ch,w,q]
    if (t < 169) {
        int p0 = (t / 13) * 4, q0 = (t % 13) * 4;
        float s[4][4];
#pragma unroll
        for (int r = 0; r < 4; ++r)
#pragma unroll
            for (int cc = 0; cc < 4; ++cc) s[r][cc] = 0.f;
        for (int w = 0; w < G5; ++w) {
            for (int ch = 0; ch < 32; ++ch) {
                const float* qr = &QKs[ch * QST + w * 49 + p0];
                const float* kr = &QKs[(32 + ch) * QST + w * 49 + q0];
                float qv[4] = {qr[0], qr[1], qr[2], qr[3]};
                float kv[4] = {kr[0], kr[1], kr[2], kr[3]};
#pragma unroll
                for (int r = 0; r < 4; ++r)
#pragma unroll
                    for (int cc = 0; cc < 4; ++cc)
                        s[r][cc] = fmaf(qv[r], kv[cc], s[r][cc]);
            }
        }
        float* sp = Spart + (long)(b * NGRP + grp) * 2401;
#pragma unroll
        for (int r = 0; r < 4; ++r) {
            int pp = p0 + r;
            if (pp < 49) {
#pragma unroll
                for (int cc = 0; cc < 4; ++cc) {
                    int qq = q0 + cc;
                    if (qq < 49) sp[pp * 49 + qq] = s[r][cc];
                }
            }
        }
    }
}

// ---------------- kred: parallel reduce of S partials ----------------
__global__ void kred(const float* __restrict__ Spart, float* __restrict__ S) {
    int tg = blockIdx.x * 256 + threadIdx.x;
    if (tg >= 8 * 2401) return;
    int b = tg / 2401, idx = tg % 2401;
    float s = 0.f;
    for (int gr = 0; gr < NGRP; ++gr) s += Spart[(long)(b * NGRP + gr) * 2401 + idx];
    S[b * 2401 + idx] = s;
}

// ---------------- ksoft: row softmax -> zero-padded bf16 attn [8][64][64] ----------------
__global__ void ksoft(const float* __restrict__ S, unsigned short* __restrict__ attnP) {
    int b = blockIdx.x, t = threadIdx.x;
    unsigned short* row = attnP + (b * 64 + t) * 64;
    if (t < 49) {
        const float* sr = S + b * 2401 + t * 49;
        float m = -1e30f;
        for (int j = 0; j < 49; ++j) m = fmaxf(m, sr[j]);
        float den = 0.f;
        for (int j = 0; j < 49; ++j) den += expf(sr[j] - m);
        float inv = 1.f / den;
        for (int j = 0; j < 49; ++j) row[j] = f2bf(expf(sr[j] - m) * inv);
        for (int j = 49; j < 64; ++j) row[j] = 0;
    } else {
        for (int j = 0; j < 64; ++j) row[j] = 0;
    }
}

// ---------------- k3: fused  Y = X·attn^T  (MFMA-1)  then  OUT = Wv·Y + bv  (MFMA-2) ----------------
__launch_bounds__(256, 3)
__global__ void k3(const float* __restrict__ x, const unsigned short* __restrict__ WvB,
                   const unsigned short* __restrict__ attnP, const float* __restrict__ bv,
                   float* __restrict__ out) {
    __shared__ __align__(16) unsigned short Xc[256 * 40];   // [c][j-half(32)+pad8] bf16
    __shared__ __align__(16) unsigned short Yt[64 * 264];   // [i][c(256)+pad8] bf16

    int t = threadIdx.x;
    int bw = blockIdx.x;
    int b = bw & 7;           // XCD swizzle: one batch per XCD, adjacent windows adjacent
    int win = bw >> 3;
    int wy = win / NH, wx = win % NH;
    int lane = t & 63;
    int r16 = lane & 15, quad = lane >> 4, q8 = quad * 8;
    int w64 = (t >> 6) * 64;

    f32x4 zero = {0.f, 0.f, 0.f, 0.f};
    f32x4 acc1[4][4];
#pragma unroll
    for (int i = 0; i < 4; ++i)
#pragma unroll
        for (int j = 0; j < 4; ++j) acc1[i][j] = zero;

    const float* xb = x + (long)b * C_ * OPLANE;

    // ---- MFMA-1: D'[c][i] = sum_j X[c][j] * attn[i][j], K split into two 32-wide halves ----
    for (int half = 0; half < 2; ++half) {
        int jbase = half * 32;
        for (int idx = t; idx < 256 * 32; idx += 256) {
            int c = idx >> 5, j0 = idx & 31, j = jbase + j0;
            float v = 0.f;
            if (j < 49) {
                int gy = wy * 7 + j / 7, gx = wx * 7 + j % 7;
                int sy = (gy < HIN) ? gy : 158;
                int sx = (gx < HIN) ? gx : 158;
                v = xb[c * OPLANE + sy * HIN + sx];
            }
            Xc[c * 40 + j0] = f2bf(v);
        }
        __syncthreads();

        int k0 = jbase;
        bf16x8 a[4], bfr[4];
#pragma unroll
        for (int mt = 0; mt < 4; ++mt)
            a[mt] = *(const bf16x8*)&Xc[(w64 + mt * 16 + r16) * 40 + q8];
#pragma unroll
        for (int nt = 0; nt < 4; ++nt)
            bfr[nt] = *(const bf16x8*)&attnP[(b * 64 + nt * 16 + r16) * 64 + k0 + q8];
#pragma unroll
        for (int mt = 0; mt < 4; ++mt)
#pragma unroll
            for (int nt = 0; nt < 4; ++nt)
                acc1[mt][nt] = __builtin_amdgcn_mfma_f32_16x16x32_bf16(a[mt], bfr[nt], acc1[mt][nt], 0, 0, 0);
        __syncthreads();
    }

    // ---- store D' transposed into Yt[i][c] (4 consecutive c per lane -> b64 writes) ----
#pragma unroll
    for (int mt = 0; mt < 4; ++mt) {
        int cb = w64 + mt * 16 + quad * 4;
#pragma unroll
        for (int nt = 0; nt < 4; ++nt) {
            int ic = nt * 16 + r16;
            u16x4 pk;
            pk[0] = f2bf(acc1[mt][nt][0]);
            pk[1] = f2bf(acc1[mt][nt][1]);
            pk[2] = f2bf(acc1[mt][nt][2]);
            pk[3] = f2bf(acc1[mt][nt][3]);
            *(u16x4*)&Yt[ic * 264 + cb] = pk;
        }
    }
    __syncthreads();

    // ---- MFMA-2: OUT[ch][i] = sum_c Wv[ch][c] * Y[c][i] ----
    f32x4 acc2[4][4];
#pragma unroll
    for (int i = 0; i < 4; ++i)
#pragma unroll
        for (int j = 0; j < 4; ++j) acc2[i][j] = zero;

#pragma unroll
    for (int ks = 0; ks < 8; ++ks) {
        int k0 = ks * 32;
        bf16x8 a[4], bb2[4];
#pragma unroll
        for (int mt = 0; mt < 4; ++mt)
            a[mt] = *(const bf16x8*)&WvB[(w64 + mt * 16 + r16) * 256 + k0 + q8];
#pragma unroll
        for (int nt = 0; nt < 4; ++nt)
            bb2[nt] = *(const bf16x8*)&Yt[(nt * 16 + r16) * 264 + k0 + q8];
#pragma unroll
        for (int mt = 0; mt < 4; ++mt)
#pragma unroll
            for (int nt = 0; nt < 4; ++nt)
                acc2[mt][nt] = __builtin_amdgcn_mfma_f32_16x16x32_bf16(a[mt], bb2[nt], acc2[mt][nt], 0, 0, 0);
    }

    // ---- epilogue: crop-write, f = win*49 + i -> (y,x) in 161x161, keep y<160 && x<160 ----
    float* ob = out + (long)b * C_ * OPLANE;
#pragma unroll
    for (int nt = 0; nt < 4; ++nt) {
        int i = nt * 16 + r16;
        if (i >= 49) continue;
        int f = win * 49 + i;
        int y = f / 161, xcol = f % 161;
        if (y >= 160 || xcol >= 160) continue;
        int dst = y * 160 + xcol;
#pragma unroll
        for (int mt = 0; mt < 4; ++mt) {
            int cb = w64 + mt * 16 + quad * 4;
#pragma unroll
            for (int r = 0; r < 4; ++r) {
                int ch = cb + r;
                ob[ch * OPLANE + dst] = acc2[mt][nt][r] + bv[ch];
            }
        }
    }
}

extern "C" void kernel_launch(void* const* d_in, const int* in_sizes, int n_in,
                              void* d_out, int out_size, void* d_ws, size_t ws_size,
                              hipStream_t stream) {
    const float* x  = (const float*)d_in[0];
    const float* Wq = (const float*)d_in[1];
    const float* bq = (const float*)d_in[2];
    const float* Wk = (const float*)d_in[3];
    const float* bk = (const float*)d_in[4];
    const float* Wv = (const float*)d_in[5];
    const float* bv = (const float*)d_in[6];
    float* out = (float*)d_out;

    char* ws = (char*)d_ws;
    unsigned short* WvB   = (unsigned short*)(ws);                        // 131072 B
    float* W2t            = (float*)(ws + 131072);                        // 65536 B
    float* Spart          = (float*)(ws + 196608);                        // 8144192 B
    float* S              = (float*)(ws + 196608 + 8144192);              // 76832 B
    unsigned short* attnP = (unsigned short*)(ws + 196608 + 8144192 + 76832); // 65536 B

    kprep<<<dim3(256), dim3(256), 0, stream>>>(Wq, Wk, Wv, WvB, W2t);
    k12<<<dim3(8 * NGRP), dim3(256), 0, stream>>>(x, W2t, bq, bk, Spart);
    kred<<<dim3(76), dim3(256), 0, stream>>>(Spart, S);
    ksoft<<<dim3(8), dim3(64), 0, stream>>>(S, attnP);
    k3<<<dim3(8 * NWIN), dim3(256), 0, stream>>>(x, WvB, attnP, bv, out);
}